// Round 1
// baseline (1077.702 us; speedup 1.0000x reference)
//
#include <hip/hip_runtime.h>
#include <stdint.h>

#define S_LEN 200
#define BATCH 1024
#define HID   128
#define VOCAB 100000

typedef __attribute__((ext_vector_type(4))) float f32x4;
typedef __attribute__((ext_vector_type(8))) short bf16x8;

__device__ __forceinline__ unsigned short f2bf(float f) {
  union { float f; uint32_t u; } v; v.f = f;
  uint32_t u = v.u;
  uint32_t r = u + 0x7fffu + ((u >> 16) & 1u);   // RNE
  return (unsigned short)(r >> 16);
}

// ---------------------------------------------------------------------------
// K1: E[v][j] = sum_k Wenc[v][k]*Wih[j][k] + bih[j] + bhh[j]
// fp32 vector GEMM, 64v x 128j block tile, 4v x 8j thread tile (interleaved)
// ---------------------------------------------------------------------------
__global__ __launch_bounds__(256) void k1_eprecomp(
    const float* __restrict__ Wenc, const float* __restrict__ Wih,
    const float* __restrict__ bih, const float* __restrict__ bhh,
    float* __restrict__ E) {
  __shared__ float Wlds[128][132];
  __shared__ float Alds[64][132];
  const int tid = threadIdx.x;
  const int v0 = blockIdx.x * 64;

  #pragma unroll
  for (int i = 0; i < 16; ++i) {                 // Wih 128x128 -> LDS
    int g = tid + i * 256;                        // float4 index
    int row = g >> 5, c4 = g & 31;
    *(f32x4*)&Wlds[row][c4 * 4] = *(const f32x4*)&Wih[row * 128 + c4 * 4];
  }
  #pragma unroll
  for (int i = 0; i < 8; ++i) {                  // Wenc tile 64x128 -> LDS
    int g = tid + i * 256;
    int row = g >> 5, c4 = g & 31;
    int v = v0 + row;
    *(f32x4*)&Alds[row][c4 * 4] =
        *(const f32x4*)&Wenc[(size_t)(v < VOCAB ? v : 0) * 128 + c4 * 4];
  }
  __syncthreads();

  const int jt = tid & 15, vt = tid >> 4;
  float acc[4][8];
  #pragma unroll
  for (int a = 0; a < 4; ++a)
    #pragma unroll
    for (int b = 0; b < 8; ++b) acc[a][b] = 0.f;

  for (int kk = 0; kk < 32; ++kk) {
    f32x4 av[4], wv[8];
    #pragma unroll
    for (int vv = 0; vv < 4; ++vv) av[vv] = *(const f32x4*)&Alds[vt + 16 * vv][kk * 4];
    #pragma unroll
    for (int jj = 0; jj < 8; ++jj) wv[jj] = *(const f32x4*)&Wlds[jt + 16 * jj][kk * 4];
    #pragma unroll
    for (int vv = 0; vv < 4; ++vv)
      #pragma unroll
      for (int jj = 0; jj < 8; ++jj)
        acc[vv][jj] += av[vv].x * wv[jj].x + av[vv].y * wv[jj].y +
                       av[vv].z * wv[jj].z + av[vv].w * wv[jj].w;
  }

  #pragma unroll
  for (int jj = 0; jj < 8; ++jj) {
    int j = jt + 16 * jj;
    float bias = bih[j] + bhh[j];
    #pragma unroll
    for (int vv = 0; vv < 4; ++vv) {
      int v = v0 + vt + 16 * vv;
      if (v < VOCAB) E[(size_t)v * 128 + j] = acc[vv][jj] + bias;
    }
  }
}

// ---------------------------------------------------------------------------
// K1b: pooling weights w[t,b]
// ---------------------------------------------------------------------------
__global__ __launch_bounds__(256) void k1b_weights(
    const float* __restrict__ t, const float* __restrict__ s,
    const int* __restrict__ length, float* __restrict__ wbuf) {
  int idx = blockIdx.x * 256 + threadIdx.x;      // S*B = 204800
  int ts = idx >> 10, b = idx & 1023;
  int len = length[b];
  float w = 0.f;
  if (ts < len) {
    int last = len - 1;
    float tl  = t[last * BATCH + b];
    float slx = s[(last * BATCH + b) * 2 + 0];
    float sly = s[(last * BATCH + b) * 2 + 1];
    float dt = tl - t[ts * BATCH + b];
    float dx = slx - s[(ts * BATCH + b) * 2 + 0];
    float dy = sly - s[(ts * BATCH + b) * 2 + 1];
    float ds = sqrtf(dx * dx + dy * dy);
    float ft = (__cosf(dt * 7.2722052166430399e-05f) + 1.f) * 0.5f *
               __expf(dt * -1.1574074074074073e-06f);
    float fs = __expf(-1000.f * ds);
    w = ft * fs + 1e-10f;
  }
  wbuf[idx] = w;
}

// ---------------------------------------------------------------------------
// K2: RNN over 200 steps + fused online pooling.
// 512 blocks x 256 thr; block owns 2 batch rows. Thread = (j = wave*32+lane/2,
// kh = lane&1) holds W_hh[j][kh*64..+64) in registers. h broadcast from LDS.
// ---------------------------------------------------------------------------
__global__ __launch_bounds__(256) void k2_rnn(
    const int* __restrict__ x, const float* __restrict__ E,
    const float* __restrict__ Whh, const float* __restrict__ h0,
    const float* __restrict__ wbuf,
    const int* __restrict__ active_user, const float* __restrict__ Wuser,
    float* __restrict__ A) {
  __shared__ float hlds[2][2][128];
  const int tid = threadIdx.x;
  const int lane = tid & 63, wv = tid >> 6;
  const int j = wv * 32 + (lane >> 1);
  const int kh = lane & 1;
  const int b0 = blockIdx.x * 2, b1 = b0 + 1;

  f32x4 Wr[16];
  const float* wrow = &Whh[j * 128 + kh * 64];
  #pragma unroll
  for (int i = 0; i < 16; ++i) Wr[i] = *(const f32x4*)&wrow[i * 4];

  { int bb = tid >> 7, jj = tid & 127;
    hlds[0][bb][jj] = h0[(b0 + bb) * 128 + jj]; }
  __syncthreads();

  float acc0 = 0.f, acc1 = 0.f, ws0 = 0.f, ws1 = 0.f;
  int xc0 = x[b0], xc1 = x[b1];
  int xn0 = x[1024 + b0], xn1 = x[1024 + b1];
  float ec0 = E[(size_t)xc0 * 128 + j], ec1 = E[(size_t)xc1 * 128 + j];
  float wc0 = wbuf[b0], wc1 = wbuf[b1];

  for (int t = 0; t < S_LEN; ++t) {
    int rb = t & 1, wb = rb ^ 1;
    int xf0 = 0, xf1 = 0;
    float en0 = 0.f, en1 = 0.f, wn0 = 0.f, wn1 = 0.f;
    if (t + 2 < S_LEN) { xf0 = x[(t + 2) * 1024 + b0]; xf1 = x[(t + 2) * 1024 + b1]; }
    if (t + 1 < S_LEN) {
      en0 = E[(size_t)xn0 * 128 + j]; en1 = E[(size_t)xn1 * 128 + j];
      wn0 = wbuf[(t + 1) * 1024 + b0]; wn1 = wbuf[(t + 1) * 1024 + b1];
    }
    float p0 = 0.f, p1 = 0.f;
    const float* h0p = &hlds[rb][0][kh * 64];
    const float* h1p = &hlds[rb][1][kh * 64];
    #pragma unroll
    for (int i = 0; i < 16; ++i) {
      f32x4 hv0 = *(const f32x4*)&h0p[i * 4];
      f32x4 hv1 = *(const f32x4*)&h1p[i * 4];
      p0 += Wr[i].x * hv0.x + Wr[i].y * hv0.y + Wr[i].z * hv0.z + Wr[i].w * hv0.w;
      p1 += Wr[i].x * hv1.x + Wr[i].y * hv1.y + Wr[i].z * hv1.z + Wr[i].w * hv1.w;
    }
    p0 += __shfl_xor(p0, 1, 64);
    p1 += __shfl_xor(p1, 1, 64);
    float hn0 = tanhf(p0 + ec0);
    float hn1 = tanhf(p1 + ec1);
    acc0 += wc0 * hn0; ws0 += wc0;
    acc1 += wc1 * hn1; ws1 += wc1;
    if (kh == 0) { hlds[wb][0][j] = hn0; hlds[wb][1][j] = hn1; }
    __syncthreads();
    xc0 = xn0; xc1 = xn1; xn0 = xf0; xn1 = xf1;
    ec0 = en0; ec1 = en1; wc0 = wn0; wc1 = wn1;
  }

  if (kh == 0) {
    A[b0 * 256 + j] = acc0 / ws0;
    A[b1 * 256 + j] = acc1 / ws1;
    int u0 = active_user[b0], u1 = active_user[b1];
    A[b0 * 256 + 128 + j] = Wuser[u0 * 128 + j];
    A[b1 * 256 + 128 + j] = Wuser[u1 * 128 + j];
  }
}

// ---------------------------------------------------------------------------
// K3: out[b][v] = sum_k A[b][k]*Wfc[v][k] + bfc[v]   (bf16 MFMA, f32 accum)
// block tile 64m x 256n, wave tile 64x64, K=256 in 8 chunks of 32.
// A staged as bf16 in LDS (row stride 264 to avoid quad-group conflicts);
// Wfc converted f32->bf16 in-register.
// ---------------------------------------------------------------------------
__global__ __launch_bounds__(256) void k3_gemm(
    const float* __restrict__ A, const float* __restrict__ Wfc,
    const float* __restrict__ bfc, float* __restrict__ out) {
  __shared__ unsigned short Alds[64 * 264];
  const int tid = threadIdx.x;
  const int nblk = blockIdx.x >> 4;    // n-outer: 16 m-blocks share a B tile
  const int mblk = blockIdx.x & 15;
  const int m0 = mblk * 64;
  const int v0 = nblk * 256;

  #pragma unroll
  for (int i = 0; i < 16; ++i) {       // A 64x256 f32 -> bf16 LDS
    int g = tid + i * 256;             // 4096 float4
    int row = g >> 6, c4 = g & 63;
    f32x4 a = *(const f32x4*)&A[(size_t)(m0 + row) * 256 + c4 * 4];
    uint2 pk;
    pk.x = (uint32_t)f2bf(a.x) | ((uint32_t)f2bf(a.y) << 16);
    pk.y = (uint32_t)f2bf(a.z) | ((uint32_t)f2bf(a.w) << 16);
    *(uint2*)((void*)&Alds[row * 264 + c4 * 4]) = pk;
  }
  __syncthreads();

  const int lane = tid & 63, wid = tid >> 6;
  const int lm = lane & 15, quad = lane >> 4;
  const int vbase = v0 + wid * 64;

  f32x4 acc[4][4];
  #pragma unroll
  for (int mt = 0; mt < 4; ++mt)
    #pragma unroll
    for (int nt = 0; nt < 4; ++nt) acc[mt][nt] = (f32x4){0.f, 0.f, 0.f, 0.f};

  const float* bptr[4];
  #pragma unroll
  for (int nt = 0; nt < 4; ++nt) {
    int v = vbase + nt * 16 + lm;
    int vc = v < VOCAB ? v : (VOCAB - 1);
    bptr[nt] = &Wfc[(size_t)vc * 256];
  }

  for (int kc = 0; kc < 8; ++kc) {
    const int k0 = kc * 32 + quad * 8;
    bf16x8 af[4], bfr[4];
    #pragma unroll
    for (int mt = 0; mt < 4; ++mt)
      af[mt] = *(const bf16x8*)&Alds[(mt * 16 + lm) * 264 + k0];
    #pragma unroll
    for (int nt = 0; nt < 4; ++nt) {
      f32x4 w0 = *(const f32x4*)&bptr[nt][k0];
      f32x4 w1 = *(const f32x4*)&bptr[nt][k0 + 4];
      bf16x8 b;
      b[0] = (short)f2bf(w0.x); b[1] = (short)f2bf(w0.y);
      b[2] = (short)f2bf(w0.z); b[3] = (short)f2bf(w0.w);
      b[4] = (short)f2bf(w1.x); b[5] = (short)f2bf(w1.y);
      b[6] = (short)f2bf(w1.z); b[7] = (short)f2bf(w1.w);
      bfr[nt] = b;
    }
    #pragma unroll
    for (int mt = 0; mt < 4; ++mt)
      #pragma unroll
      for (int nt = 0; nt < 4; ++nt)
        acc[mt][nt] = __builtin_amdgcn_mfma_f32_16x16x32_bf16(
            af[mt], bfr[nt], acc[mt][nt], 0, 0, 0);
  }

  #pragma unroll
  for (int nt = 0; nt < 4; ++nt) {
    int v = vbase + nt * 16 + lm;
    if (v >= VOCAB) continue;
    float bias = bfc[v];
    #pragma unroll
    for (int mt = 0; mt < 4; ++mt) {
      int row = m0 + mt * 16 + quad * 4;
      #pragma unroll
      for (int r = 0; r < 4; ++r)
        out[(size_t)(row + r) * VOCAB + v] = acc[mt][nt][r] + bias;
    }
  }
}

// ---------------------------------------------------------------------------
extern "C" void kernel_launch(void* const* d_in, const int* in_sizes, int n_in,
                              void* d_out, int out_size, void* d_ws, size_t ws_size,
                              hipStream_t stream) {
  const int*   x     = (const int*)d_in[0];
  const float* t     = (const float*)d_in[1];
  const float* s     = (const float*)d_in[2];
  // d_in[3] = y_t, d_in[4] = y_s  (unused by reference)
  const float* h0    = (const float*)d_in[5];
  const int*   au    = (const int*)d_in[6];
  const int*   len   = (const int*)d_in[7];
  const float* Wenc  = (const float*)d_in[8];
  const float* Wuser = (const float*)d_in[9];
  const float* Wih   = (const float*)d_in[10];
  const float* Whh   = (const float*)d_in[11];
  const float* bih   = (const float*)d_in[12];
  const float* bhh   = (const float*)d_in[13];
  const float* Wfc   = (const float*)d_in[14];
  const float* bfc   = (const float*)d_in[15];
  float* out = (float*)d_out;

  char* ws = (char*)d_ws;
  float* E    = (float*)(ws);                    // 100000*128*4 = 51,200,000 B
  float* wbuf = (float*)(ws + 51200000);         // 200*1024*4  =    819,200 B
  float* A    = (float*)(ws + 52019200);         // 1024*256*4  =  1,048,576 B

  k1_eprecomp<<<1563, 256, 0, stream>>>(Wenc, Wih, bih, bhh, E);
  k1b_weights<<<800, 256, 0, stream>>>(t, s, len, wbuf);
  k2_rnn<<<512, 256, 0, stream>>>(x, E, Whh, h0, wbuf, au, Wuser, A);
  k3_gemm<<<6256, 256, 0, stream>>>(A, Wfc, bfc, out);
}